// Round 1
// baseline (291.839 us; speedup 1.0000x reference)
//
#include <hip/hip_runtime.h>
#include <hip/hip_bf16.h>

typedef __bf16 bf16_t;
typedef __bf16 bf16x8 __attribute__((ext_vector_type(8)));
typedef float f32x4 __attribute__((ext_vector_type(4)));

#define MFMA16(a, b, c) __builtin_amdgcn_mfma_f32_16x16x32_bf16(a, b, c, 0, 0, 0)

// Problem constants
// B=4, T=4096, E=1024, H=64
static constexpr float LOG2E = 1.44269504088896340736f;
static constexpr float QSCALE = LOG2E / 32.0f;  // E^-0.5 * log2(e), folded into q

// ws layout (bytes):
//   qs  [16384][64] bf16 @ 0        (2 MB)  -- q * QSCALE
//   ks  [16384][64] bf16 @ 2 MB     (2 MB)
//   vt  [4][64][4096] bf16 @ 4 MB   (2 MB)  -- v transposed per batch
//   wt  [3][64][1024] bf16 @ 6 MB   (384 KB) -- W^T, bf16

__global__ void transpose_w_kernel(const float* __restrict__ Wq,
                                   const float* __restrict__ Wk,
                                   const float* __restrict__ Wv,
                                   bf16_t* __restrict__ wt) {
    int idx = blockIdx.x * 256 + threadIdx.x;          // 3*64*1024 threads
    int w = idx >> 16;
    int rem = idx & 65535;
    int col = rem >> 10;
    int e = rem & 1023;
    const float* W = (w == 0) ? Wq : ((w == 1) ? Wk : Wv);
    wt[idx] = (bf16_t)W[e * 64 + col];                 // wt[w][col][e], coalesced store
}

// 1024 blocks x 192 threads. Wave 0/1/2 -> q/k/v. Each block: 16 rows of x.
__global__ void proj_kernel(const float* __restrict__ x, const bf16_t* __restrict__ wt,
                            bf16_t* __restrict__ qs, bf16_t* __restrict__ ks,
                            bf16_t* __restrict__ vt) {
    int wave = threadIdx.x >> 6;
    int lane = threadIdx.x & 63;
    int lr = lane & 15, lg = lane >> 4;
    int r0 = blockIdx.x * 16;

    const float* xp = x + (size_t)(r0 + lr) * 1024 + lg * 8;
    const bf16_t* wtp = wt + wave * 65536 + lr * 1024 + lg * 8;

    f32x4 acc[4];
#pragma unroll
    for (int cs = 0; cs < 4; ++cs) acc[cs] = (f32x4){0.f, 0.f, 0.f, 0.f};

#pragma unroll 4
    for (int ec = 0; ec < 32; ++ec) {
        float4 a0 = *(const float4*)(xp + ec * 32);
        float4 a1 = *(const float4*)(xp + ec * 32 + 4);
        bf16x8 af;
        af[0] = (bf16_t)a0.x; af[1] = (bf16_t)a0.y; af[2] = (bf16_t)a0.z; af[3] = (bf16_t)a0.w;
        af[4] = (bf16_t)a1.x; af[5] = (bf16_t)a1.y; af[6] = (bf16_t)a1.z; af[7] = (bf16_t)a1.w;
        bf16x8 b0 = *(const bf16x8*)(wtp + 0 * 16384 + ec * 32);
        bf16x8 b1 = *(const bf16x8*)(wtp + 1 * 16384 + ec * 32);
        bf16x8 b2 = *(const bf16x8*)(wtp + 2 * 16384 + ec * 32);
        bf16x8 b3 = *(const bf16x8*)(wtp + 3 * 16384 + ec * 32);
        acc[0] = MFMA16(af, b0, acc[0]);
        acc[1] = MFMA16(af, b1, acc[1]);
        acc[2] = MFMA16(af, b2, acc[2]);
        acc[3] = MFMA16(af, b3, acc[3]);
    }

#pragma unroll
    for (int cs = 0; cs < 4; ++cs) {
        int h = cs * 16 + lr;
#pragma unroll
        for (int reg = 0; reg < 4; ++reg) {
            int r = r0 + lg * 4 + reg;  // D layout: row=(lane>>4)*4+reg, col=lane&15
            float v = acc[cs][reg];
            if (wave == 0) {
                qs[(size_t)r * 64 + h] = (bf16_t)(v * QSCALE);
            } else if (wave == 1) {
                ks[(size_t)r * 64 + h] = (bf16_t)v;
            } else {
                int bb = r >> 12, t = r & 4095;
                vt[(size_t)(bb * 64 + h) * 4096 + t] = (bf16_t)v;
            }
        }
    }
}

// 1024 blocks x 64 threads (1 wave). Each wave: 16 q rows, iterate 32-key tiles.
__global__ __launch_bounds__(64) void attn_kernel(const bf16_t* __restrict__ qs,
                                                  const bf16_t* __restrict__ ks,
                                                  const bf16_t* __restrict__ vt,
                                                  float* __restrict__ out) {
    __shared__ bf16_t pl[16 * 40];  // P tile [16 q][32 keys], rows padded to 40 elems (80 B)
    int lane = threadIdx.x;
    int lr = lane & 15, lg = lane >> 4;
    int b = blockIdx.x >> 8;
    int j = blockIdx.x & 255;
    // triangle remap: balance causal work across co-resident blocks
    int qt = (j & 1) ? (255 - (j >> 1)) : (j >> 1);
    int q0 = qt * 16;

    const bf16_t* qb = qs + (size_t)(b * 4096 + q0 + lr) * 64 + lg * 8;
    bf16x8 qf0 = *(const bf16x8*)(qb);
    bf16x8 qf1 = *(const bf16x8*)(qb + 32);

    f32x4 o0 = {0.f, 0.f, 0.f, 0.f}, o1 = o0, o2 = o0, o3 = o0;
    float m[4], l[4];
#pragma unroll
    for (int r = 0; r < 4; ++r) { m[r] = -INFINITY; l[r] = 0.f; }

    int nt = (q0 + 15) / 32 + 1;
    const bf16_t* kbase = ks + (size_t)(b * 4096) * 64 + lr * 64 + lg * 8;
    const bf16_t* vbase = vt + (size_t)(b * 64 + lr) * 4096 + lg * 8;

    for (int it = 0; it < nt; ++it) {
        int kb = it * 32;
        const bf16_t* kp = kbase + (size_t)kb * 64;
        bf16x8 k00 = *(const bf16x8*)(kp);
        bf16x8 k01 = *(const bf16x8*)(kp + 32);
        bf16x8 k10 = *(const bf16x8*)(kp + 16 * 64);
        bf16x8 k11 = *(const bf16x8*)(kp + 16 * 64 + 32);
        const bf16_t* vp = vbase + kb;
        bf16x8 v0 = *(const bf16x8*)(vp);
        bf16x8 v1 = *(const bf16x8*)(vp + 16 * 4096);
        bf16x8 v2 = *(const bf16x8*)(vp + 32 * 4096);
        bf16x8 v3 = *(const bf16x8*)(vp + 48 * 4096);

        f32x4 z = {0.f, 0.f, 0.f, 0.f};
        f32x4 s0 = MFMA16(qf0, k00, z);
        s0 = MFMA16(qf1, k01, s0);
        f32x4 s1 = MFMA16(qf0, k10, z);
        s1 = MFMA16(qf1, k11, s1);

        if (kb + 31 > q0) {  // diagonal tile: causal mask
#pragma unroll
            for (int r = 0; r < 4; ++r) {
                int qrow = q0 + lg * 4 + r;
                if (kb + lr > qrow) s0[r] = -INFINITY;
                if (kb + 16 + lr > qrow) s1[r] = -INFINITY;
            }
        }

        float p0[4], p1[4], al[4];
#pragma unroll
        for (int r = 0; r < 4; ++r) {
            float t = fmaxf(s0[r], s1[r]);
            t = fmaxf(t, __shfl_xor(t, 1));
            t = fmaxf(t, __shfl_xor(t, 2));
            t = fmaxf(t, __shfl_xor(t, 4));
            t = fmaxf(t, __shfl_xor(t, 8));
            float mn = fmaxf(m[r], t);
            float a = __builtin_amdgcn_exp2f(m[r] - mn);  // m=-inf first iter -> 0, no NaN
            p0[r] = __builtin_amdgcn_exp2f(s0[r] - mn);
            p1[r] = __builtin_amdgcn_exp2f(s1[r] - mn);
            float rs = p0[r] + p1[r];
            rs += __shfl_xor(rs, 1);
            rs += __shfl_xor(rs, 2);
            rs += __shfl_xor(rs, 4);
            rs += __shfl_xor(rs, 8);
            l[r] = l[r] * a + rs;
            m[r] = mn;
            al[r] = a;
        }
#pragma unroll
        for (int r = 0; r < 4; ++r) {
            o0[r] *= al[r]; o1[r] *= al[r]; o2[r] *= al[r]; o3[r] *= al[r];
        }

        // P -> LDS (bf16), then re-read as A-fragment (8 contiguous keys/lane)
#pragma unroll
        for (int r = 0; r < 4; ++r) {
            int row = lg * 4 + r;
            pl[row * 40 + lr] = (bf16_t)p0[r];
            pl[row * 40 + 16 + lr] = (bf16_t)p1[r];
        }
        __syncthreads();
        bf16x8 pa = *(const bf16x8*)(pl + lr * 40 + lg * 8);
        o0 = MFMA16(pa, v0, o0);
        o1 = MFMA16(pa, v1, o1);
        o2 = MFMA16(pa, v2, o2);
        o3 = MFMA16(pa, v3, o3);
        __syncthreads();
    }

    float rl[4];
#pragma unroll
    for (int r = 0; r < 4; ++r) rl[r] = 1.0f / l[r];
    float* ob = out + (size_t)(b * 4096 + q0 + lg * 4) * 64 + lr;
#pragma unroll
    for (int r = 0; r < 4; ++r) {
        ob[r * 64 + 0]  = o0[r] * rl[r];
        ob[r * 64 + 16] = o1[r] * rl[r];
        ob[r * 64 + 32] = o2[r] * rl[r];
        ob[r * 64 + 48] = o3[r] * rl[r];
    }
}

extern "C" void kernel_launch(void* const* d_in, const int* in_sizes, int n_in,
                              void* d_out, int out_size, void* d_ws, size_t ws_size,
                              hipStream_t stream) {
    const float* x  = (const float*)d_in[0];
    const float* Wq = (const float*)d_in[1];
    const float* Wk = (const float*)d_in[2];
    const float* Wv = (const float*)d_in[3];
    float* out = (float*)d_out;

    char* ws = (char*)d_ws;
    bf16_t* qs = (bf16_t*)(ws);
    bf16_t* ks = (bf16_t*)(ws + (2u << 20));
    bf16_t* vt = (bf16_t*)(ws + (4u << 20));
    bf16_t* wt = (bf16_t*)(ws + (6u << 20));

    transpose_w_kernel<<<768, 256, 0, stream>>>(Wq, Wk, Wv, wt);
    proj_kernel<<<1024, 192, 0, stream>>>(x, wt, qs, ks, vt);
    attn_kernel<<<1024, 64, 0, stream>>>(qs, ks, vt, out);
}

// Round 3
// 260.624 us; speedup vs baseline: 1.1198x; 1.1198x over previous
//
#include <hip/hip_runtime.h>
#include <hip/hip_bf16.h>

typedef __bf16 bf16_t;
typedef __bf16 bf16x8 __attribute__((ext_vector_type(8)));
typedef float f32x4 __attribute__((ext_vector_type(4)));

#define MFMA16(a, b, c) __builtin_amdgcn_mfma_f32_16x16x32_bf16(a, b, c, 0, 0, 0)

// B=4, T=4096, E=1024, H=64
static constexpr float LOG2E = 1.44269504088896340736f;
static constexpr float QSCALE = LOG2E / 32.0f;  // E^-0.5 * log2(e), folded into q

// ws layout (bytes):
//   qs  [16384][64] bf16 @ 0        (2 MB)  -- q * QSCALE
//   ks  [16384][64] bf16 @ 2 MB     (2 MB)
//   vt  [4][64][4096] bf16 @ 4 MB   (2 MB)  -- v transposed per batch
//   wt  [3][64][1024] bf16 @ 6 MB   (384 KB) -- W^T, bf16

__global__ void transpose_w_kernel(const float* __restrict__ Wq,
                                   const float* __restrict__ Wk,
                                   const float* __restrict__ Wv,
                                   bf16_t* __restrict__ wt) {
    int idx = blockIdx.x * 256 + threadIdx.x;
    int w = idx >> 16;
    int rem = idx & 65535;
    int col = rem >> 10;
    int e = rem & 1023;
    const float* W = (w == 0) ? Wq : ((w == 1) ? Wk : Wv);
    wt[idx] = (bf16_t)W[e * 64 + col];  // wt[w][col][e]
}

// 1024 blocks x 256 threads. Block: 16 rows of x, ALL 192 output cols.
// Waves split K=1024 into 4 chunks of 256; LDS f32 reduce at the end.
__global__ __launch_bounds__(256, 4) void proj_kernel(const float* __restrict__ x,
                                                      const bf16_t* __restrict__ wt,
                                                      bf16_t* __restrict__ qs,
                                                      bf16_t* __restrict__ ks,
                                                      bf16_t* __restrict__ vt) {
    __shared__ float red[3][12][16][16];  // partials from waves 1..3: [w-1][chunk][row][col]
    int wave = threadIdx.x >> 6;
    int lane = threadIdx.x & 63;
    int lr = lane & 15, lg = lane >> 4;
    int r0 = blockIdx.x * 16;

    const float* xp = x + (size_t)(r0 + lr) * 1024 + wave * 256 + lg * 8;
    const bf16_t* wtp = wt + lr * 1024 + wave * 256 + lg * 8;

    f32x4 acc[12];
#pragma unroll
    for (int c = 0; c < 12; ++c) acc[c] = (f32x4){0.f, 0.f, 0.f, 0.f};

#pragma unroll
    for (int ec = 0; ec < 8; ++ec) {
        float4 a0 = *(const float4*)(xp + ec * 32);
        float4 a1 = *(const float4*)(xp + ec * 32 + 4);
        bf16x8 af;
        af[0] = (bf16_t)a0.x; af[1] = (bf16_t)a0.y; af[2] = (bf16_t)a0.z; af[3] = (bf16_t)a0.w;
        af[4] = (bf16_t)a1.x; af[5] = (bf16_t)a1.y; af[6] = (bf16_t)a1.z; af[7] = (bf16_t)a1.w;
#pragma unroll
        for (int w3 = 0; w3 < 3; ++w3) {
#pragma unroll
            for (int cc = 0; cc < 4; ++cc) {
                bf16x8 bf = *(const bf16x8*)(wtp + w3 * 65536 + cc * 16384 + ec * 32);
                acc[w3 * 4 + cc] = MFMA16(af, bf, acc[w3 * 4 + cc]);
            }
        }
    }

    if (wave != 0) {
#pragma unroll
        for (int c = 0; c < 12; ++c)
#pragma unroll
            for (int r = 0; r < 4; ++r)
                red[wave - 1][c][lg * 4 + r][lr] = acc[c][r];
    }
    __syncthreads();
    if (wave == 0) {
#pragma unroll
        for (int c = 0; c < 12; ++c) {
            int w3 = c >> 2, cc = c & 3;
            int h = cc * 16 + lr;
#pragma unroll
            for (int r = 0; r < 4; ++r) {
                int row = lg * 4 + r;
                float sum = acc[c][r] + red[0][c][row][lr] + red[1][c][row][lr] + red[2][c][row][lr];
                int rr = r0 + row;
                if (w3 == 0) {
                    qs[(size_t)rr * 64 + h] = (bf16_t)(sum * QSCALE);
                } else if (w3 == 1) {
                    ks[(size_t)rr * 64 + h] = (bf16_t)sum;
                } else {
                    vt[(size_t)((rr >> 12) * 64 + h) * 4096 + (rr & 4095)] = (bf16_t)sum;
                }
            }
        }
    }
}

// 1024 blocks x 256 threads (4 waves). Block: 16 q rows; waves split the key
// range (strided 64-key tiles), private (m,l,o) merged via LDS at the end.
__global__ __launch_bounds__(256, 4) void attn_kernel(const bf16_t* __restrict__ qs,
                                                      const bf16_t* __restrict__ ks,
                                                      const bf16_t* __restrict__ vt,
                                                      float* __restrict__ out) {
    __shared__ bf16_t pl[4][16][72];        // per-wave P tile [16 q][64 k], pad to 72
    __shared__ float lo[4][4][16][16];      // [wave][hchunk][row][col]
    __shared__ float lm[4][16], ll[4][16];  // [wave][row]
    int wave = threadIdx.x >> 6;
    int lane = threadIdx.x & 63;
    int lr = lane & 15, lg = lane >> 4;
    int b = blockIdx.x >> 8;
    int j = blockIdx.x & 255;
    int qt = (j & 1) ? (255 - (j >> 1)) : (j >> 1);  // triangle balance
    int q0 = qt * 16;

    const bf16_t* qb = qs + (size_t)(b * 4096 + q0 + lr) * 64 + lg * 8;
    bf16x8 qf0 = *(const bf16x8*)(qb);
    bf16x8 qf1 = *(const bf16x8*)(qb + 32);

    f32x4 o0 = {0.f, 0.f, 0.f, 0.f}, o1 = o0, o2 = o0, o3 = o0;
    float m[4], l[4];
#pragma unroll
    for (int r = 0; r < 4; ++r) { m[r] = -INFINITY; l[r] = 0.f; }

    int nt = (q0 >> 6) + 1;  // 64-key tiles up to the diagonal
    const bf16_t* kbase = ks + (size_t)(b * 4096) * 64 + lr * 64 + lg * 8;
    const bf16_t* vbase = vt + (size_t)(b * 64 + lr) * 4096 + lg * 8;

    for (int it = wave; it < nt; it += 4) {
        int kb = it * 64;
        f32x4 z = {0.f, 0.f, 0.f, 0.f};
        f32x4 s[4];
#pragma unroll
        for (int g = 0; g < 4; ++g) {
            const bf16_t* kp = kbase + (size_t)(kb + g * 16) * 64;
            bf16x8 k0 = *(const bf16x8*)(kp);
            bf16x8 k1 = *(const bf16x8*)(kp + 32);
            s[g] = MFMA16(qf0, k0, z);
            s[g] = MFMA16(qf1, k1, s[g]);
        }

        if (it == nt - 1) {  // diagonal tile: causal mask
#pragma unroll
            for (int r = 0; r < 4; ++r) {
                int qrow = q0 + lg * 4 + r;
#pragma unroll
                for (int g = 0; g < 4; ++g)
                    if (kb + g * 16 + lr > qrow) s[g][r] = -INFINITY;
            }
        }

        float p[4][4];
#pragma unroll
        for (int r = 0; r < 4; ++r) {
            float t = fmaxf(fmaxf(s[0][r], s[1][r]), fmaxf(s[2][r], s[3][r]));
            t = fmaxf(t, __shfl_xor(t, 1));
            t = fmaxf(t, __shfl_xor(t, 2));
            t = fmaxf(t, __shfl_xor(t, 4));
            t = fmaxf(t, __shfl_xor(t, 8));
            float mn = fmaxf(m[r], t);
            float a = __builtin_amdgcn_exp2f(m[r] - mn);
#pragma unroll
            for (int g = 0; g < 4; ++g) p[g][r] = __builtin_amdgcn_exp2f(s[g][r] - mn);
            float rs = (p[0][r] + p[1][r]) + (p[2][r] + p[3][r]);
            rs += __shfl_xor(rs, 1);
            rs += __shfl_xor(rs, 2);
            rs += __shfl_xor(rs, 4);
            rs += __shfl_xor(rs, 8);
            l[r] = l[r] * a + rs;
            m[r] = mn;
            o0[r] *= a; o1[r] *= a; o2[r] *= a; o3[r] *= a;
        }

        // P -> private LDS slice (no cross-wave sharing -> no barrier needed)
#pragma unroll
        for (int r = 0; r < 4; ++r)
#pragma unroll
            for (int g = 0; g < 4; ++g)
                pl[wave][lg * 4 + r][g * 16 + lr] = (bf16_t)p[g][r];

        bf16x8 pa0 = *(const bf16x8*)(&pl[wave][lr][lg * 8]);
        bf16x8 pa1 = *(const bf16x8*)(&pl[wave][lr][32 + lg * 8]);

        const bf16_t* vp = vbase + kb;
        bf16x8 v00 = *(const bf16x8*)(vp);
        bf16x8 v01 = *(const bf16x8*)(vp + 32);
        bf16x8 v10 = *(const bf16x8*)(vp + 16 * 4096);
        bf16x8 v11 = *(const bf16x8*)(vp + 16 * 4096 + 32);
        bf16x8 v20 = *(const bf16x8*)(vp + 32 * 4096);
        bf16x8 v21 = *(const bf16x8*)(vp + 32 * 4096 + 32);
        bf16x8 v30 = *(const bf16x8*)(vp + 48 * 4096);
        bf16x8 v31 = *(const bf16x8*)(vp + 48 * 4096 + 32);
        o0 = MFMA16(pa0, v00, o0); o0 = MFMA16(pa1, v01, o0);
        o1 = MFMA16(pa0, v10, o1); o1 = MFMA16(pa1, v11, o1);
        o2 = MFMA16(pa0, v20, o2); o2 = MFMA16(pa1, v21, o2);
        o3 = MFMA16(pa0, v30, o3); o3 = MFMA16(pa1, v31, o3);
    }

    // publish partials
#pragma unroll
    for (int r = 0; r < 4; ++r) {
        int row = lg * 4 + r;
        lo[wave][0][row][lr] = o0[r];
        lo[wave][1][row][lr] = o1[r];
        lo[wave][2][row][lr] = o2[r];
        lo[wave][3][row][lr] = o3[r];
        if (lr == r) { lm[wave][row] = m[r]; ll[wave][row] = l[r]; }
    }
    __syncthreads();

    // each wave finalizes one 16-col output chunk
#pragma unroll
    for (int r = 0; r < 4; ++r) {
        int row = lg * 4 + r;
        float m0 = lm[0][row], m1 = lm[1][row], m2 = lm[2][row], m3 = lm[3][row];
        float M = fmaxf(fmaxf(m0, m1), fmaxf(m2, m3));
        float s0 = __builtin_amdgcn_exp2f(m0 - M);
        float s1 = __builtin_amdgcn_exp2f(m1 - M);
        float s2 = __builtin_amdgcn_exp2f(m2 - M);
        float s3 = __builtin_amdgcn_exp2f(m3 - M);
        float L = ll[0][row] * s0 + ll[1][row] * s1 + ll[2][row] * s2 + ll[3][row] * s3;
        float val = lo[0][wave][row][lr] * s0 + lo[1][wave][row][lr] * s1 +
                    lo[2][wave][row][lr] * s2 + lo[3][wave][row][lr] * s3;
        out[(size_t)(b * 4096 + q0 + row) * 64 + wave * 16 + lr] = val / L;
    }
}

extern "C" void kernel_launch(void* const* d_in, const int* in_sizes, int n_in,
                              void* d_out, int out_size, void* d_ws, size_t ws_size,
                              hipStream_t stream) {
    const float* x  = (const float*)d_in[0];
    const float* Wq = (const float*)d_in[1];
    const float* Wk = (const float*)d_in[2];
    const float* Wv = (const float*)d_in[3];
    float* out = (float*)d_out;

    char* ws = (char*)d_ws;
    bf16_t* qs = (bf16_t*)(ws);
    bf16_t* ks = (bf16_t*)(ws + (2u << 20));
    bf16_t* vt = (bf16_t*)(ws + (4u << 20));
    bf16_t* wt = (bf16_t*)(ws + (6u << 20));

    transpose_w_kernel<<<768, 256, 0, stream>>>(Wq, Wk, Wv, wt);
    proj_kernel<<<1024, 256, 0, stream>>>(x, wt, qs, ks, vt);
    attn_kernel<<<1024, 256, 0, stream>>>(qs, ks, vt, out);
}

// Round 4
// 242.452 us; speedup vs baseline: 1.2037x; 1.0749x over previous
//
#include <hip/hip_runtime.h>
#include <hip/hip_bf16.h>

typedef __bf16 bf16_t;
typedef __bf16 bf16x8 __attribute__((ext_vector_type(8)));
typedef float f32x4 __attribute__((ext_vector_type(4)));

#define MFMA16(a, b, c) __builtin_amdgcn_mfma_f32_16x16x32_bf16(a, b, c, 0, 0, 0)

// B=4, T=4096, E=1024, H=64
static constexpr float LOG2E = 1.44269504088896340736f;
static constexpr float QSCALE = LOG2E / 32.0f;  // E^-0.5 * log2(e), folded into q

// ws layout (bytes):
//   qs  [16384][64] bf16 @ 0        (2 MB)  -- q * QSCALE
//   ks  [16384][64] bf16 @ 2 MB     (2 MB)
//   vt  [4][64][4096] bf16 @ 4 MB   (2 MB)  -- v transposed per batch
//   wt  [3][64][1024] bf16 @ 6 MB   (384 KB) -- W^T, bf16

// ---- DPP 16-lane-row reduces (VALU latency, no LDS round trip) ----
template <int CTRL>
__device__ __forceinline__ float dppf(float v) {
    return __builtin_bit_cast(
        float, __builtin_amdgcn_mov_dpp(__builtin_bit_cast(int, v), CTRL, 0xf, 0xf, true));
}
__device__ __forceinline__ float rmax16(float t) {
    t = fmaxf(t, dppf<0xB1>(t));   // quad_perm [1,0,3,2]  (xor 1)
    t = fmaxf(t, dppf<0x4E>(t));   // quad_perm [2,3,0,1]  (xor 2)
    t = fmaxf(t, dppf<0x141>(t));  // row_half_mirror
    t = fmaxf(t, dppf<0x140>(t));  // row_mirror
    return t;
}
__device__ __forceinline__ float rsum16(float t) {
    t += dppf<0xB1>(t);
    t += dppf<0x4E>(t);
    t += dppf<0x141>(t);
    t += dppf<0x140>(t);
    return t;
}

// 48 blocks x 256 threads: LDS tile transpose, coalesced both sides.
__global__ __launch_bounds__(256) void transpose_w_kernel(const float* __restrict__ Wq,
                                                          const float* __restrict__ Wk,
                                                          const float* __restrict__ Wv,
                                                          bf16_t* __restrict__ wt) {
    __shared__ float tile[64][68];
    int w = blockIdx.x >> 4;           // 0..2
    int e0 = (blockIdx.x & 15) * 64;   // e-tile base
    const float* W = (w == 0) ? Wq : ((w == 1) ? Wk : Wv);
    int t = threadIdx.x;
    int r = t >> 2, q = t & 3;
    const float* src = W + (size_t)(e0 + r) * 64 + q * 16;
#pragma unroll
    for (int jj = 0; jj < 4; ++jj) {
        float4 v = *(const float4*)(src + jj * 4);
        *(float4*)&tile[r][q * 16 + jj * 4] = v;
    }
    __syncthreads();
    // thread: output col r, e-chunk q*16..+15 -> two bf16x8 coalesced stores
    bf16_t* dst = wt + (size_t)w * 65536 + (size_t)r * 1024 + e0 + q * 16;
    bf16x8 o0, o1;
#pragma unroll
    for (int jj = 0; jj < 8; ++jj) o0[jj] = (bf16_t)tile[q * 16 + jj][r];
#pragma unroll
    for (int jj = 0; jj < 8; ++jj) o1[jj] = (bf16_t)tile[q * 16 + 8 + jj][r];
    *(bf16x8*)dst = o0;
    *(bf16x8*)(dst + 8) = o1;
}

// 1024 blocks x 256 threads. Stage 16 x-rows in LDS (bf16), then each wave
// owns 48 output cols x full K=1024. No cross-wave reduce, own stores.
__global__ __launch_bounds__(256) void proj_kernel(const float* __restrict__ x,
                                                   const bf16_t* __restrict__ wt,
                                                   bf16_t* __restrict__ qs,
                                                   bf16_t* __restrict__ ks,
                                                   bf16_t* __restrict__ vt) {
    __shared__ bf16_t xl[16][1040];  // pad 16 to break row-stride aliasing
    int t = threadIdx.x;
    int r0 = blockIdx.x * 16;
    {
        int row = t >> 4, cb = (t & 15) * 4;
        const float* xr = x + (size_t)(r0 + row) * 1024 + cb;
#pragma unroll
        for (int i = 0; i < 16; ++i) {
            float4 v = *(const float4*)(xr + i * 64);
            bf16_t* d = &xl[row][cb + i * 64];
            d[0] = (bf16_t)v.x; d[1] = (bf16_t)v.y; d[2] = (bf16_t)v.z; d[3] = (bf16_t)v.w;
        }
    }
    __syncthreads();

    int wave = t >> 6, lane = t & 63;
    int lr = lane & 15, lg = lane >> 4;
    int gc0 = wave * 3;  // 3 col-chunks of 16 per wave
    const bf16_t* wp0 = wt + ((gc0 + 0) >> 2) * 65536 + (((gc0 + 0) & 3) * 16 + lr) * 1024 + lg * 8;
    const bf16_t* wp1 = wt + ((gc0 + 1) >> 2) * 65536 + (((gc0 + 1) & 3) * 16 + lr) * 1024 + lg * 8;
    const bf16_t* wp2 = wt + ((gc0 + 2) >> 2) * 65536 + (((gc0 + 2) & 3) * 16 + lr) * 1024 + lg * 8;

    f32x4 a0 = {0.f, 0.f, 0.f, 0.f}, a1 = a0, a2 = a0;
#pragma unroll 4
    for (int kk = 0; kk < 32; ++kk) {
        bf16x8 af = *(const bf16x8*)&xl[lr][kk * 32 + lg * 8];
        bf16x8 b0 = *(const bf16x8*)(wp0 + kk * 32);
        bf16x8 b1 = *(const bf16x8*)(wp1 + kk * 32);
        bf16x8 b2 = *(const bf16x8*)(wp2 + kk * 32);
        a0 = MFMA16(af, b0, a0);
        a1 = MFMA16(af, b1, a1);
        a2 = MFMA16(af, b2, a2);
    }

    f32x4 accs[3] = {a0, a1, a2};
#pragma unroll
    for (int c = 0; c < 3; ++c) {
        int gc = gc0 + c;
        int w3 = gc >> 2;
        int h = (gc & 3) * 16 + lr;
#pragma unroll
        for (int r = 0; r < 4; ++r) {
            int rr = r0 + lg * 4 + r;
            float v = accs[c][r];
            if (w3 == 0) {
                qs[(size_t)rr * 64 + h] = (bf16_t)(v * QSCALE);
            } else if (w3 == 1) {
                ks[(size_t)rr * 64 + h] = (bf16_t)v;
            } else {
                vt[(size_t)((rr >> 12) * 64 + h) * 4096 + (rr & 4095)] = (bf16_t)v;
            }
        }
    }
}

// 1024 blocks x 512 threads (8 waves). Block: 16 q rows; waves split the key
// range (strided 32-key tiles); DPP softmax; LDS merge at end.
__global__ __launch_bounds__(512) void attn_kernel(const bf16_t* __restrict__ qs,
                                                   const bf16_t* __restrict__ ks,
                                                   const bf16_t* __restrict__ vt,
                                                   float* __restrict__ out) {
    __shared__ bf16_t pl[8][16][40];        // per-wave P tile [16 q][32 k]
    __shared__ float lo[8][4][16][16];      // [wave][hchunk][row][col]
    __shared__ float lm[8][16], ll[8][16];  // [wave][row]
    int wave = threadIdx.x >> 6, lane = threadIdx.x & 63;
    int lr = lane & 15, lg = lane >> 4;
    int b = blockIdx.x >> 8, j = blockIdx.x & 255;
    int qt = (j & 1) ? (255 - (j >> 1)) : (j >> 1);  // triangle balance
    int q0 = qt * 16;

    const bf16_t* qb = qs + (size_t)(b * 4096 + q0 + lr) * 64 + lg * 8;
    bf16x8 qf0 = *(const bf16x8*)(qb);
    bf16x8 qf1 = *(const bf16x8*)(qb + 32);

    f32x4 o0 = {0.f, 0.f, 0.f, 0.f}, o1 = o0, o2 = o0, o3 = o0;
    float m[4], l[4];
#pragma unroll
    for (int r = 0; r < 4; ++r) { m[r] = -INFINITY; l[r] = 0.f; }

    int nt = (q0 >> 5) + 1;  // 32-key tiles up to the diagonal
    const bf16_t* kbase = ks + (size_t)b * 4096 * 64 + lr * 64 + lg * 8;
    const bf16_t* vbase = vt + ((size_t)b * 64 + lr) * 4096 + lg * 8;

    for (int it = wave; it < nt; it += 8) {
        int kb = it * 32;
        const bf16_t* kp = kbase + (size_t)kb * 64;
        bf16x8 k00 = *(const bf16x8*)(kp);
        bf16x8 k01 = *(const bf16x8*)(kp + 32);
        bf16x8 k10 = *(const bf16x8*)(kp + 16 * 64);
        bf16x8 k11 = *(const bf16x8*)(kp + 16 * 64 + 32);
        const bf16_t* vp = vbase + kb;
        bf16x8 v0 = *(const bf16x8*)(vp);
        bf16x8 v1 = *(const bf16x8*)(vp + 16 * 4096);
        bf16x8 v2 = *(const bf16x8*)(vp + 32 * 4096);
        bf16x8 v3 = *(const bf16x8*)(vp + 48 * 4096);

        f32x4 z = {0.f, 0.f, 0.f, 0.f};
        f32x4 s0 = MFMA16(qf0, k00, z);
        s0 = MFMA16(qf1, k01, s0);
        f32x4 s1 = MFMA16(qf0, k10, z);
        s1 = MFMA16(qf1, k11, s1);

        if (it == nt - 1) {  // diagonal tile: causal mask
#pragma unroll
            for (int r = 0; r < 4; ++r) {
                int qrow = q0 + lg * 4 + r;
                if (kb + lr > qrow) s0[r] = -INFINITY;
                if (kb + 16 + lr > qrow) s1[r] = -INFINITY;
            }
        }

#pragma unroll
        for (int r = 0; r < 4; ++r) {
            float t2 = rmax16(fmaxf(s0[r], s1[r]));
            float mn = fmaxf(m[r], t2);
            float a = __builtin_amdgcn_exp2f(m[r] - mn);
            float p0 = __builtin_amdgcn_exp2f(s0[r] - mn);
            float p1 = __builtin_amdgcn_exp2f(s1[r] - mn);
            float rs = rsum16(p0 + p1);
            l[r] = l[r] * a + rs;
            m[r] = mn;
            o0[r] *= a; o1[r] *= a; o2[r] *= a; o3[r] *= a;
            pl[wave][lg * 4 + r][lr] = (bf16_t)p0;
            pl[wave][lg * 4 + r][16 + lr] = (bf16_t)p1;
        }

        bf16x8 pa = *(const bf16x8*)&pl[wave][lr][lg * 8];
        o0 = MFMA16(pa, v0, o0);
        o1 = MFMA16(pa, v1, o1);
        o2 = MFMA16(pa, v2, o2);
        o3 = MFMA16(pa, v3, o3);
    }

    // publish partials
#pragma unroll
    for (int r = 0; r < 4; ++r) {
        int row = lg * 4 + r;
        lo[wave][0][row][lr] = o0[r];
        lo[wave][1][row][lr] = o1[r];
        lo[wave][2][row][lr] = o2[r];
        lo[wave][3][row][lr] = o3[r];
        if (lr == r) { lm[wave][row] = m[r]; ll[wave][row] = l[r]; }
    }
    __syncthreads();

    // merge: wave -> (col-chunk wave&3, row-half wave>>2)
    int hc = wave & 3;
    int rb = (wave >> 2) * 8;
#pragma unroll
    for (int r2 = 0; r2 < 2; ++r2) {
        int row = rb + lg * 2 + r2;
        float M = -INFINITY;
#pragma unroll
        for (int w = 0; w < 8; ++w) M = fmaxf(M, lm[w][row]);
        float L = 0.f, val = 0.f;
#pragma unroll
        for (int w = 0; w < 8; ++w) {
            float sw = __builtin_amdgcn_exp2f(lm[w][row] - M);
            L += ll[w][row] * sw;
            val += lo[w][hc][row][lr] * sw;
        }
        out[(size_t)(b * 4096 + q0 + row) * 64 + hc * 16 + lr] = val / L;
    }
}

extern "C" void kernel_launch(void* const* d_in, const int* in_sizes, int n_in,
                              void* d_out, int out_size, void* d_ws, size_t ws_size,
                              hipStream_t stream) {
    const float* x  = (const float*)d_in[0];
    const float* Wq = (const float*)d_in[1];
    const float* Wk = (const float*)d_in[2];
    const float* Wv = (const float*)d_in[3];
    float* out = (float*)d_out;

    char* ws = (char*)d_ws;
    bf16_t* qs = (bf16_t*)(ws);
    bf16_t* ks = (bf16_t*)(ws + (2u << 20));
    bf16_t* vt = (bf16_t*)(ws + (4u << 20));
    bf16_t* wt = (bf16_t*)(ws + (6u << 20));

    transpose_w_kernel<<<48, 256, 0, stream>>>(Wq, Wk, Wv, wt);
    proj_kernel<<<1024, 256, 0, stream>>>(x, wt, qs, ks, vt);
    attn_kernel<<<1024, 512, 0, stream>>>(qs, ks, vt, out);
}

// Round 5
// 191.069 us; speedup vs baseline: 1.5274x; 1.2689x over previous
//
#include <hip/hip_runtime.h>
#include <hip/hip_bf16.h>

typedef __bf16 bf16_t;
typedef __bf16 bf16x4 __attribute__((ext_vector_type(4)));
typedef __bf16 bf16x8 __attribute__((ext_vector_type(8)));
typedef float f32x4 __attribute__((ext_vector_type(4)));

#define MFMA16(a, b, c) __builtin_amdgcn_mfma_f32_16x16x32_bf16(a, b, c, 0, 0, 0)

// B=4, T=4096, E=1024, H=64
static constexpr float LOG2E = 1.44269504088896340736f;
static constexpr float QSCALE = LOG2E / 32.0f;  // E^-0.5 * log2(e), folded into q

// ws layout (bytes):
//   qs  [16384][64] bf16 @ 0     (2 MB)   q * QSCALE
//   ks  [16384][64] bf16 @ 2 MB  (2 MB)
//   vt  [4][64][4096] bf16 @ 4 MB (2 MB)  v transposed per batch
//   wt  [3][64][1024] bf16 @ 6 MB (384 KB)
//   po  [512][64][64] bf16 @ 8 MB (4 MB)  split-K partial O
//   pm  [512][64] f32 @ 12 MB (128 KB)    partial running max
//   pls [512][64] f32 @ 12.125 MB (128 KB) partial running sum

// ---- DPP 16-lane-row reduces ----
template <int CTRL>
__device__ __forceinline__ float dppf(float v) {
    return __builtin_bit_cast(
        float, __builtin_amdgcn_mov_dpp(__builtin_bit_cast(int, v), CTRL, 0xf, 0xf, true));
}
__device__ __forceinline__ float rmax16(float t) {
    t = fmaxf(t, dppf<0xB1>(t));
    t = fmaxf(t, dppf<0x4E>(t));
    t = fmaxf(t, dppf<0x141>(t));
    t = fmaxf(t, dppf<0x140>(t));
    return t;
}
__device__ __forceinline__ float rsum16(float t) {
    t += dppf<0xB1>(t);
    t += dppf<0x4E>(t);
    t += dppf<0x141>(t);
    t += dppf<0x140>(t);
    return t;
}

// 48 blocks x 256: LDS tile transpose, coalesced both sides.
__global__ __launch_bounds__(256) void transpose_w_kernel(const float* __restrict__ Wq,
                                                          const float* __restrict__ Wk,
                                                          const float* __restrict__ Wv,
                                                          bf16_t* __restrict__ wt) {
    __shared__ float tile[64][68];
    int w = blockIdx.x >> 4;
    int e0 = (blockIdx.x & 15) * 64;
    const float* W = (w == 0) ? Wq : ((w == 1) ? Wk : Wv);
    int t = threadIdx.x;
    int r = t >> 2, q = t & 3;
    const float* src = W + (size_t)(e0 + r) * 64 + q * 16;
#pragma unroll
    for (int jj = 0; jj < 4; ++jj) {
        float4 v = *(const float4*)(src + jj * 4);
        *(float4*)&tile[r][q * 16 + jj * 4] = v;
    }
    __syncthreads();
    bf16_t* dst = wt + (size_t)w * 65536 + (size_t)r * 1024 + e0 + q * 16;
    bf16x8 o0, o1;
#pragma unroll
    for (int jj = 0; jj < 8; ++jj) o0[jj] = (bf16_t)tile[q * 16 + jj][r];
#pragma unroll
    for (int jj = 0; jj < 8; ++jj) o1[jj] = (bf16_t)tile[q * 16 + 8 + jj][r];
    *(bf16x8*)dst = o0;
    *(bf16x8*)(dst + 8) = o1;
}

// 1024 blocks x 256. Stage 16 x-rows in LDS bf16; wave owns 48 cols x K=1024.
// v-part stores transposed through LDS (coalesced), q/k direct.
__global__ __launch_bounds__(256) void proj_kernel(const float* __restrict__ x,
                                                   const bf16_t* __restrict__ wt,
                                                   bf16_t* __restrict__ qs,
                                                   bf16_t* __restrict__ ks,
                                                   bf16_t* __restrict__ vt) {
    __shared__ __align__(16) bf16_t xl[16][1040];
    __shared__ float vred[64][17];
    int t = threadIdx.x;
    int r0 = blockIdx.x * 16;
    {
        int row = t >> 4, cb = (t & 15) * 4;
        const float* xr = x + (size_t)(r0 + row) * 1024 + cb;
#pragma unroll
        for (int i = 0; i < 16; ++i) {
            float4 v = *(const float4*)(xr + i * 64);
            bf16_t* d = &xl[row][cb + i * 64];
            d[0] = (bf16_t)v.x; d[1] = (bf16_t)v.y; d[2] = (bf16_t)v.z; d[3] = (bf16_t)v.w;
        }
    }
    __syncthreads();

    int wave = t >> 6, lane = t & 63;
    int lr = lane & 15, lg = lane >> 4;
    int gc0 = wave * 3;
    const bf16_t* wp0 = wt + ((gc0 + 0) >> 2) * 65536 + (((gc0 + 0) & 3) * 16 + lr) * 1024 + lg * 8;
    const bf16_t* wp1 = wt + ((gc0 + 1) >> 2) * 65536 + (((gc0 + 1) & 3) * 16 + lr) * 1024 + lg * 8;
    const bf16_t* wp2 = wt + ((gc0 + 2) >> 2) * 65536 + (((gc0 + 2) & 3) * 16 + lr) * 1024 + lg * 8;

    f32x4 a0 = {0.f, 0.f, 0.f, 0.f}, a1 = a0, a2 = a0;
#pragma unroll 4
    for (int kk = 0; kk < 32; ++kk) {
        bf16x8 af = *(const bf16x8*)&xl[lr][kk * 32 + lg * 8];
        bf16x8 b0 = *(const bf16x8*)(wp0 + kk * 32);
        bf16x8 b1 = *(const bf16x8*)(wp1 + kk * 32);
        bf16x8 b2 = *(const bf16x8*)(wp2 + kk * 32);
        a0 = MFMA16(af, b0, a0);
        a1 = MFMA16(af, b1, a1);
        a2 = MFMA16(af, b2, a2);
    }

    f32x4 accs[3] = {a0, a1, a2};
#pragma unroll
    for (int c = 0; c < 3; ++c) {
        int gc = gc0 + c;
        int w3 = gc >> 2;
        int h = (gc & 3) * 16 + lr;
#pragma unroll
        for (int r = 0; r < 4; ++r) {
            int rr = r0 + lg * 4 + r;
            float v = accs[c][r];
            if (w3 == 0) {
                qs[(size_t)rr * 64 + h] = (bf16_t)(v * QSCALE);
            } else if (w3 == 1) {
                ks[(size_t)rr * 64 + h] = (bf16_t)v;
            } else {
                vred[(gc - 8) * 16 + lr][lg * 4 + r] = v;  // [v-col][t-local]
            }
        }
    }
    __syncthreads();
    // cooperative vt store: thread -> (h = t>>2, 4 t-values)
    {
        int h = t >> 2, j4 = (t & 3) * 4;
        int bb = r0 >> 12, t0 = r0 & 4095;
        bf16x4 v4;
#pragma unroll
        for (int jj = 0; jj < 4; ++jj) v4[jj] = (bf16_t)vred[h][j4 + jj];
        *(bf16x4*)(vt + ((size_t)(bb * 64 + h)) * 4096 + t0 + j4) = v4;
    }
}

// 512 blocks x 256 (4 waves): {b:4} x {qt:64 of QBLK=64 rows} x {split:2}.
// Wave w owns rows q0+16w..+16 (no cross-wave merge). K/V tiles (64 keys)
// cooperatively staged in LDS, double-buffered, prefetch-before-compute.
__global__ __launch_bounds__(256) void attn_kernel(const bf16_t* __restrict__ qs,
                                                   const bf16_t* __restrict__ ks,
                                                   const bf16_t* __restrict__ vt,
                                                   bf16_t* __restrict__ po,
                                                   float* __restrict__ pm,
                                                   float* __restrict__ pls) {
    __shared__ __align__(16) bf16_t kt[2][64 * 64];
    __shared__ __align__(16) bf16_t vtl[2][64 * 64];
    __shared__ __align__(16) bf16_t pl[4][16][80];

    int tid = threadIdx.x;
    int wave = tid >> 6, lane = tid & 63;
    int lr = lane & 15, lg = lane >> 4;

    int bid = blockIdx.x;
    int s = bid & 1;
    int jq = (bid >> 1) & 63;
    int b = bid >> 7;
    int qt = (jq & 1) ? (63 - (jq >> 1)) : (jq >> 1);  // triangle balance
    int q0 = qt << 6;
    int nk = qt + 1;                    // 64-key tiles up to diagonal
    int lo = (nk * s) >> 1;
    int hi = (nk * (s + 1)) >> 1;
    int ntile = hi - lo;

    // staging: thread covers slots (srow, sc) and (srow+32, sc); both-sides swizzle
    int srow = tid >> 3, sc = tid & 7;
    int sw8 = srow & 7;  // (srow+32)&7 == srow&7
    int koff0 = srow * 64 + ((sc ^ sw8) * 8);
    int koff1 = (32 + srow) * 64 + ((sc ^ sw8) * 8);
    const bf16_t* kg = ks + ((size_t)b * 4096) * 64;
    const bf16_t* vg = vt + ((size_t)b * 64) * 4096;

    const bf16_t* qb = qs + (size_t)(b * 4096 + q0 + wave * 16 + lr) * 64 + lg * 8;
    bf16x8 qf0 = *(const bf16x8*)qb;
    bf16x8 qf1 = *(const bf16x8*)(qb + 32);

    f32x4 o[4];
    float m[4], l[4];
#pragma unroll
    for (int r = 0; r < 4; ++r) {
        o[r] = (f32x4){0.f, 0.f, 0.f, 0.f};
        m[r] = -INFINITY;
        l[r] = 0.f;
    }

    bf16x8 kr0, kr1, vr0, vr1;
    if (ntile > 0) {
        int kb = lo << 6;
        kr0 = *(const bf16x8*)(kg + (size_t)(kb + srow) * 64 + sc * 8);
        kr1 = *(const bf16x8*)(kg + (size_t)(kb + 32 + srow) * 64 + sc * 8);
        vr0 = *(const bf16x8*)(vg + (size_t)srow * 4096 + kb + sc * 8);
        vr1 = *(const bf16x8*)(vg + (size_t)(32 + srow) * 4096 + kb + sc * 8);
    }

    for (int ti = 0; ti < ntile; ++ti) {
        int cur = ti & 1;
        *(bf16x8*)(&kt[cur][koff0]) = kr0;
        *(bf16x8*)(&kt[cur][koff1]) = kr1;
        *(bf16x8*)(&vtl[cur][koff0]) = vr0;
        *(bf16x8*)(&vtl[cur][koff1]) = vr1;
        __syncthreads();
        if (ti + 1 < ntile) {  // prefetch next tile; in flight during compute
            int kb = (lo + ti + 1) << 6;
            kr0 = *(const bf16x8*)(kg + (size_t)(kb + srow) * 64 + sc * 8);
            kr1 = *(const bf16x8*)(kg + (size_t)(kb + 32 + srow) * 64 + sc * 8);
            vr0 = *(const bf16x8*)(vg + (size_t)srow * 4096 + kb + sc * 8);
            vr1 = *(const bf16x8*)(vg + (size_t)(32 + srow) * 4096 + kb + sc * 8);
        }

        int gt = lo + ti;
        int kb = gt << 6;
        const bf16_t* kbuf = kt[cur];
        const bf16_t* vbuf = vtl[cur];

        f32x4 z = {0.f, 0.f, 0.f, 0.f};
        f32x4 sv[4];
#pragma unroll
        for (int g = 0; g < 4; ++g) {
            int krow = g * 16 + lr;
            int sw = krow & 7;
            bf16x8 kf0 = *(const bf16x8*)(kbuf + krow * 64 + ((lg ^ sw) * 8));
            bf16x8 kf1 = *(const bf16x8*)(kbuf + krow * 64 + (((4 | lg) ^ sw) * 8));
            sv[g] = MFMA16(qf0, kf0, z);
            sv[g] = MFMA16(qf1, kf1, sv[g]);
        }

        if (gt == nk - 1) {  // diagonal tile
#pragma unroll
            for (int r = 0; r < 4; ++r) {
                int qrow = q0 + wave * 16 + lg * 4 + r;
#pragma unroll
                for (int g = 0; g < 4; ++g)
                    if (kb + g * 16 + lr > qrow) sv[g][r] = -INFINITY;
            }
        }

#pragma unroll
        for (int r = 0; r < 4; ++r) {
            float t2 = fmaxf(fmaxf(sv[0][r], sv[1][r]), fmaxf(sv[2][r], sv[3][r]));
            t2 = rmax16(t2);
            float mn = fmaxf(m[r], t2);
            float a = __builtin_amdgcn_exp2f(m[r] - mn);
            float p0 = __builtin_amdgcn_exp2f(sv[0][r] - mn);
            float p1 = __builtin_amdgcn_exp2f(sv[1][r] - mn);
            float p2 = __builtin_amdgcn_exp2f(sv[2][r] - mn);
            float p3 = __builtin_amdgcn_exp2f(sv[3][r] - mn);
            float rs = rsum16((p0 + p1) + (p2 + p3));
            l[r] = l[r] * a + rs;
            m[r] = mn;
            o[0][r] *= a; o[1][r] *= a; o[2][r] *= a; o[3][r] *= a;
            int prow = lg * 4 + r;
            pl[wave][prow][lr] = (bf16_t)p0;
            pl[wave][prow][16 + lr] = (bf16_t)p1;
            pl[wave][prow][32 + lr] = (bf16_t)p2;
            pl[wave][prow][48 + lr] = (bf16_t)p3;
        }

        bf16x8 pa0 = *(const bf16x8*)&pl[wave][lr][lg * 8];
        bf16x8 pa1 = *(const bf16x8*)&pl[wave][lr][32 + lg * 8];
#pragma unroll
        for (int oc = 0; oc < 4; ++oc) {
            int drow = oc * 16 + lr;
            int sw = drow & 7;
            bf16x8 vf0 = *(const bf16x8*)(vbuf + drow * 64 + ((lg ^ sw) * 8));
            bf16x8 vf1 = *(const bf16x8*)(vbuf + drow * 64 + (((4 | lg) ^ sw) * 8));
            o[oc] = MFMA16(pa0, vf0, o[oc]);
            o[oc] = MFMA16(pa1, vf1, o[oc]);
        }
    }

    // partial outputs (unnormalized o, m, l)
    size_t pblk = ((size_t)((b << 6) + qt) << 1) + s;
    bf16_t* pop = po + pblk * 4096;
#pragma unroll
    for (int r = 0; r < 4; ++r) {
        int row = wave * 16 + lg * 4 + r;
#pragma unroll
        for (int oc = 0; oc < 4; ++oc) pop[row * 64 + oc * 16 + lr] = (bf16_t)o[oc][r];
        if (lr == r) {
            pm[pblk * 64 + row] = m[r];
            pls[pblk * 64 + row] = l[r];
        }
    }
}

// 256 blocks x 256: merge the 2 key-splits per row, normalize, write f32 out.
__global__ __launch_bounds__(256) void merge_kernel(const bf16_t* __restrict__ po,
                                                    const float* __restrict__ pm,
                                                    const float* __restrict__ pls,
                                                    float* __restrict__ out) {
    int gid = blockIdx.x * 256 + threadIdx.x;  // 65536 = 16384 rows x 4 col-chunks
    int row = gid >> 2, cq = gid & 3;
    int b = row >> 12, t = row & 4095;
    int qt = t >> 6, lrow = t & 63;
    int pb = ((b << 6) + qt) << 1;

    float m0 = pm[(size_t)pb * 64 + lrow];
    float m1 = pm[(size_t)(pb + 1) * 64 + lrow];
    float M = fmaxf(m0, m1);
    float w0 = (m0 == -INFINITY) ? 0.f : __builtin_amdgcn_exp2f(m0 - M);
    float w1 = (m1 == -INFINITY) ? 0.f : __builtin_amdgcn_exp2f(m1 - M);
    float L = pls[(size_t)pb * 64 + lrow] * w0 + pls[(size_t)(pb + 1) * 64 + lrow] * w1;
    float rL = 1.0f / L;

    const bf16_t* p0 = po + ((size_t)pb * 64 + lrow) * 64 + cq * 16;
    const bf16_t* p1 = po + ((size_t)(pb + 1) * 64 + lrow) * 64 + cq * 16;
    bf16x8 x0 = *(const bf16x8*)p0, x1 = *(const bf16x8*)(p0 + 8);
    bf16x8 y0 = *(const bf16x8*)p1, y1 = *(const bf16x8*)(p1 + 8);
    float* op = out + (size_t)row * 64 + cq * 16;
#pragma unroll
    for (int j = 0; j < 8; ++j) op[j] = (w0 * (float)x0[j] + w1 * (float)y0[j]) * rL;
#pragma unroll
    for (int j = 0; j < 8; ++j) op[8 + j] = (w0 * (float)x1[j] + w1 * (float)y1[j]) * rL;
}

extern "C" void kernel_launch(void* const* d_in, const int* in_sizes, int n_in,
                              void* d_out, int out_size, void* d_ws, size_t ws_size,
                              hipStream_t stream) {
    const float* x  = (const float*)d_in[0];
    const float* Wq = (const float*)d_in[1];
    const float* Wk = (const float*)d_in[2];
    const float* Wv = (const float*)d_in[3];
    float* out = (float*)d_out;

    char* ws = (char*)d_ws;
    bf16_t* qs = (bf16_t*)(ws);
    bf16_t* ks = (bf16_t*)(ws + (2u << 20));
    bf16_t* vt = (bf16_t*)(ws + (4u << 20));
    bf16_t* wt = (bf16_t*)(ws + (6u << 20));
    bf16_t* po = (bf16_t*)(ws + (8u << 20));
    float*  pm = (float*)(ws + (12u << 20));
    float*  pls = (float*)(ws + (12u << 20) + (128u << 10));

    transpose_w_kernel<<<48, 256, 0, stream>>>(Wq, Wk, Wv, wt);
    proj_kernel<<<1024, 256, 0, stream>>>(x, wt, qs, ks, vt);
    attn_kernel<<<512, 256, 0, stream>>>(qs, ks, vt, po, pm, pls);
    merge_kernel<<<256, 256, 0, stream>>>(po, pm, pls, out);
}